// Round 1
// baseline (258.718 us; speedup 1.0000x reference)
//
#include <hip/hip_runtime.h>

#define NX 8192
#define NKNOTS 132
#define NCOEFS 128

// ---------------------------------------------------------------------------
// Kernel 1: evaluate the cubic B-spline at all 8192 x points (with coefs) and
// all 8192 t points (with coefs_2). gid < NX -> x, else t.
// Span search replicates the reference's degree-0 indicator semantics
// (knots[i] <= v < knots[i+1]) using the *actual* knot values, then the
// de Boor window recursion computes the 4 nonzero basis values.
// ---------------------------------------------------------------------------
__global__ void spline_eval_kernel(const float* __restrict__ x,
                                   const float* __restrict__ t,
                                   const float* __restrict__ knots,
                                   const float* __restrict__ coefs,
                                   const float* __restrict__ coefs_2,
                                   float* __restrict__ out_vals) {
    __shared__ float kn[NKNOTS];
    __shared__ float cf[2 * NCOEFS];
    if (threadIdx.x < NKNOTS) kn[threadIdx.x] = knots[threadIdx.x];
    if (threadIdx.x < NCOEFS) {
        cf[threadIdx.x] = coefs[threadIdx.x];
        cf[NCOEFS + threadIdx.x] = coefs_2[threadIdx.x];
    }
    __syncthreads();

    int gid = blockIdx.x * blockDim.x + threadIdx.x;
    if (gid >= 2 * NX) return;

    const bool is_t = (gid >= NX);
    const float v = is_t ? t[gid - NX] : x[gid];
    const float* c = is_t ? (cf + NCOEFS) : cf;

    // knots[3 + k] = k/125 for k = 0..125 (open-uniform). Initial guess then
    // correct with the exact comparisons the reference uses.
    int span = 3 + (int)(v * 125.0f);
    span = min(127, max(3, span));
    while (span > 3 && v < kn[span]) span--;
    while (span < 127 && v >= kn[span + 1]) span++;

    // de Boor: N[0..3] = values of B_{span-3..span} at v.
    float N[4];
    float left[4], right[4];
    N[0] = 1.0f;
    #pragma unroll
    for (int j = 1; j <= 3; ++j) {
        left[j]  = v - kn[span + 1 - j];
        right[j] = kn[span + j] - v;
        float saved = 0.0f;
        #pragma unroll
        for (int r = 0; r < j; ++r) {
            float temp = N[r] / (right[r + 1] + left[j - r]);
            N[r] = saved + right[r + 1] * temp;
            saved = left[j - r] * temp;
        }
        N[j] = saved;
    }

    float s = 0.0f;
    #pragma unroll
    for (int r = 0; r <= 3; ++r) s += c[span - 3 + r] * N[r];

    out_vals[gid] = s;
}

// ---------------------------------------------------------------------------
// Kernel 2: out[i][j] = sx[i] * st[j], float4-vectorized stores.
// vals[0..NX-1] = sx, vals[NX..2NX-1] = st.
// Each thread writes one float4 (4 consecutive j). 2048 float4 per row.
// ---------------------------------------------------------------------------
__global__ void outer_kernel(const float* __restrict__ vals,
                             float4* __restrict__ out) {
    const int gid = blockIdx.x * blockDim.x + threadIdx.x;  // 0 .. 8192*2048-1
    const int j4 = gid & 2047;       // float4 column
    const int i  = gid >> 11;        // row

    const float sx = vals[i];
    const float4 st = ((const float4*)(vals + NX))[j4];

    float4 o;
    o.x = sx * st.x;
    o.y = sx * st.y;
    o.z = sx * st.z;
    o.w = sx * st.w;
    out[(size_t)i * 2048 + j4] = o;
}

extern "C" void kernel_launch(void* const* d_in, const int* in_sizes, int n_in,
                              void* d_out, int out_size, void* d_ws, size_t ws_size,
                              hipStream_t stream) {
    const float* x       = (const float*)d_in[0];
    const float* t       = (const float*)d_in[1];
    const float* knots   = (const float*)d_in[2];
    const float* coefs   = (const float*)d_in[3];
    const float* coefs_2 = (const float*)d_in[4];
    float* out = (float*)d_out;
    float* ws  = (float*)d_ws;   // 2*NX floats of spline values

    // Kernel 1: 16384 evals
    spline_eval_kernel<<<(2 * NX) / 256, 256, 0, stream>>>(x, t, knots, coefs,
                                                           coefs_2, ws);

    // Kernel 2: 8192 rows * 2048 float4 cols
    const long long total = (long long)NX * 2048;
    outer_kernel<<<(int)(total / 256), 256, 0, stream>>>(ws, (float4*)out);
}